// Round 16
// baseline (182.951 us; speedup 1.0000x reference)
//
#include <hip/hip_runtime.h>
#include <hip/hip_bf16.h>

// MultiHeadAttention: B=4 S=2048 D=1024 H=16 DK=DV=64 scale=8
// R16: gemm reshaped to the attn-proven configuration — 256x128 tile, 8 waves
// (4Mx2N, wave tile 64x64 unchanged), TWO K-tiles per barrier interval
// (32 MFMA/barrier, was 16), A in 4-buf LDS (stage next pair during interval;
// entry barrier retires prior reads -> WAR-safe), B register-direct (R15).
// One PIPE_BAR(4)/interval. Evidence: 4 gemm structures pinned at 84us/0.61PF
// while attn runs 1.11PF with exactly this shape; R9/R10 attn ladder +22%
// from the same change. attn/conv/proj frozen.

typedef unsigned short u16;
typedef unsigned int   u32;
typedef short bf16x8 __attribute__((ext_vector_type(8)));
typedef short bf16x4 __attribute__((ext_vector_type(4)));
typedef float f32x4  __attribute__((ext_vector_type(4)));
typedef u32   u32x4  __attribute__((ext_vector_type(4)));

#define S_TOT 2048
#define HD    1024
#define QK_SCALE 0.18033688f   // log2(e)/8

#if __has_builtin(__builtin_amdgcn_exp2f)
#define EXP2(x) __builtin_amdgcn_exp2f(x)
#else
#define EXP2(x) exp2f(x)
#endif

__device__ __forceinline__ u16 f2bf(float f) {
  union { float f; unsigned u; } v; v.f = f;
  unsigned r = v.u + 0x7FFFu + ((v.u >> 16) & 1u);
  return (u16)(r >> 16);
}

__device__ __forceinline__ u32 cvt_pk_bf16(float lo, float hi) {
  u32 r;
  asm("v_cvt_pk_bf16_f32 %0, %1, %2" : "=v"(r) : "v"(lo), "v"(hi));
  return r;
}

__device__ __forceinline__ bf16x4 ds_tr16(unsigned a) {
  bf16x4 d;
  asm volatile("ds_read_b64_tr_b16 %0, %1" : "=v"(d) : "v"(a) : "memory");
  return d;
}

__device__ __forceinline__ void gld16(const u16* g, u16* l) {
  __builtin_amdgcn_global_load_lds(
      (const __attribute__((address_space(1))) u32*)g,
      (__attribute__((address_space(3))) u32*)l, 16, 0, 0);
}

// rule #18 fence — used ONLY by the fallback proj
#define LGKM_FENCE() do { asm volatile("s_waitcnt lgkmcnt(0)" ::: "memory"); \
                          __builtin_amdgcn_sched_barrier(0); } while (0)

// counted-vmcnt phase boundary: keep N newest VMEM ops in flight across barrier
#define PIPE_BAR(N) do { asm volatile("s_waitcnt vmcnt(" #N ")" ::: "memory"); \
                         __builtin_amdgcn_s_barrier(); \
                         __builtin_amdgcn_sched_barrier(0); } while (0)

// ---------------------------------------------------------------------------
// conv_kernel (frozen): fp32 -> bf16 re-layout.
//  Xb: row-major, intra-32 split-K perm, + XOR swizzle ((row&6)<<2)  [A: LDS]
//  Wt: W^T tiles [(nb*32+kb)][128 n][32 kperm], NO swizzle            [B: reg]
// ---------------------------------------------------------------------------
__global__ __launch_bounds__(256)
void conv_kernel(const float* __restrict__ x0, const float* __restrict__ x1, const float* __restrict__ x2,
                 const float* __restrict__ w0, const float* __restrict__ w1, const float* __restrict__ w2,
                 u16* __restrict__ Xb, u16* __restrict__ Wt)
{
  const int z = blockIdx.y;
  const int t = threadIdx.x;
  if (blockIdx.x < 1024) {
    const float* X = z == 0 ? x0 : (z == 1 ? x1 : x2);
    u16* Xz = Xb + (size_t)z * 8388608;
    int tid = blockIdx.x * 256 + t;
#pragma unroll
    for (int i = 0; i < 8; ++i) {
      int c = tid + i * 262144;
      int row = c >> 8, k4 = (c & 255) * 4;
      const float4 xv = *(const float4*)&X[(size_t)row * 1024 + k4];
      int p = (k4 & ~31) + 8 * ((k4 & 15) >> 2) + 4 * ((k4 >> 4) & 1);
      p ^= (row & 6) << 2;
      bf16x4 sv = { (short)f2bf(xv.x), (short)f2bf(xv.y), (short)f2bf(xv.z), (short)f2bf(xv.w) };
      *(bf16x4*)&Xz[(size_t)row * 1024 + p] = sv;
    }
  } else {
    const float* W = z == 0 ? w0 : (z == 1 ? w1 : w2);
    u16* Wz = Wt + (size_t)z * 1048576;
    int tid = (blockIdx.x - 1024) * 256 + t;
#pragma unroll
    for (int i = 0; i < 8; ++i) {
      int c = tid + i * 32768;
      int n = c & 1023, k4 = (c >> 10) * 4;
      float wv0 = W[(size_t)(k4 + 0) * 1024 + n];
      float wv1 = W[(size_t)(k4 + 1) * 1024 + n];
      float wv2 = W[(size_t)(k4 + 2) * 1024 + n];
      float wv3 = W[(size_t)(k4 + 3) * 1024 + n];
      int kl = k4 & 31;
      int kp = 8 * ((kl & 15) >> 2) + 4 * ((kl >> 4) & 1);
      int off = ((n >> 7) * 32 + (k4 >> 5)) * 4096 + (n & 127) * 32 + kp;
      bf16x4 sv = { (short)f2bf(wv0), (short)f2bf(wv1), (short)f2bf(wv2), (short)f2bf(wv3) };
      *(bf16x4*)&Wz[off] = sv;
    }
  }
}

// ---------------------------------------------------------------------------
// gemm_kernel R16: 256x128 tile, 8 waves (4Mx2N), 2 K-tiles/interval, A in
// 4-buf LDS (counted vmcnt), B global->reg ping-pong. z<2: natural. z==2->vT.
// ---------------------------------------------------------------------------
__global__ __launch_bounds__(512)
void gemm_kernel(const u16* __restrict__ Xb, const u16* __restrict__ Wt,
                 const float* __restrict__ b0, const float* __restrict__ b1, const float* __restrict__ b2,
                 u16* __restrict__ o0, u16* __restrict__ o1, u16* __restrict__ vT)
{
  // bijective XCD swizzle: nwg=768 (%8==0), 96 contiguous work ids per XCD
  int p  = blockIdx.x + 8 * blockIdx.y + 256 * blockIdx.z;
  int wk = (p & 7) * 96 + (p >> 3);
  int nb = wk & 7, mb = (wk >> 3) & 31, z = wk >> 8;

  const u16* Xz = Xb + (size_t)z * 8388608;
  const u16* Wz = Wt + (size_t)z * 1048576;
  const float* BS = z == 0 ? b0 : (z == 1 ? b1 : b2);
  const float  osc = (z == 0) ? QK_SCALE : 1.0f;

  const int t = threadIdx.x;
  const int lane = t & 63, wid = t >> 6;
  const int g = lane >> 4, ln = lane & 15;
  const int wm = wid >> 1;                       // M-quarter (0..3)
  const int whalf = wid & 1;                     // N-half (0..1)
  const int mbase = mb * 256, nbase = nb * 128;
  const int xr = (ln & 6) << 2;                  // A read-side swizzle (u16)

  __shared__ __align__(16) u16 Al[4][256 * 32];  // 4 x 16KB (A only)

  f32x4 acc[4][4];
#pragma unroll
  for (int i = 0; i < 4; ++i)
#pragma unroll
    for (int j = 0; j < 4; ++j) { acc[i][j][0]=0.f; acc[i][j][1]=0.f; acc[i][j][2]=0.f; acc[i][j][3]=0.f; }

  // A staging: 512 threads cover 256 rows x 32 kperm in 2 gld16 rounds
  const u16* sa = Xz + (size_t)(mbase + (t >> 2)) * 1024 + (t & 3) * 8;
  u16* alw[4] = { &Al[0][wid * 512], &Al[1][wid * 512], &Al[2][wid * 512], &Al[3][wid * 512] };

  auto stage = [&](int kb, int buf) __attribute__((always_inline)) {
    gld16(sa + kb * 32,                alw[buf]);
    gld16(sa + kb * 32 + 128 * 1024,   alw[buf] + 4096);
  };

  // B fragment source: wave's 64-col half of the 128-col W^T panel
  const u16* wfp = Wz + (size_t)(nb * 32) * 4096 + (whalf * 64 + ln) * 32 + g * 8;
  auto loadB = [&](int kb, bf16x8* dst) __attribute__((always_inline)) {
#pragma unroll
    for (int nf = 0; nf < 4; ++nf)
      dst[nf] = *(const bf16x8*)(wfp + (size_t)kb * 4096 + nf * 512);
  };

  bf16x8 bA[4], bB[4];

  // prologue: A tiles 0,1 -> bufs 0,1; B tile 0; wait A0,A1 (keep B0 in flight)
  stage(0, 0);
  stage(1, 1);
  loadB(0, bA);
  PIPE_BAR(4);

  if (z < 2) {
    u16* O = z == 0 ? o0 : o1;

    auto compute = [&](int cur, const bf16x8* bq) __attribute__((always_inline)) {
      bf16x8 af[4];
#pragma unroll
      for (int mf = 0; mf < 4; ++mf)
        af[mf] = *(const bf16x8*)&Al[cur][(wm * 64 + mf * 16 + ln) * 32 + (g * 8 ^ xr)];
      __builtin_amdgcn_s_setprio(1);
#pragma unroll
      for (int mf = 0; mf < 4; ++mf)
#pragma unroll
        for (int nf = 0; nf < 4; ++nf)
          acc[mf][nf] = __builtin_amdgcn_mfma_f32_16x16x32_bf16(af[mf], bq[nf], acc[mf][nf], 0, 0, 0);
      __builtin_amdgcn_s_setprio(0);
    };

    // intervals 0..13 (tiles 0..27), unrolled x2 for literal buffer indices
    for (int j = 0; j < 14; j += 2) {
      int kb = 2 * j;
      stage(kb + 2, 2); stage(kb + 3, 3); loadB(kb + 1, bB); compute(0, bA);
      loadB(kb + 2, bA); compute(1, bB); PIPE_BAR(4);
      stage(kb + 4, 0); stage(kb + 5, 1); loadB(kb + 3, bB); compute(2, bA);
      loadB(kb + 4, bA); compute(3, bB); PIPE_BAR(4);
    }
    // interval 14: tiles 28,29 (bufs 0,1), stage 30,31
    stage(30, 2); stage(31, 3); loadB(29, bB); compute(0, bA);
    loadB(30, bA); compute(1, bB); PIPE_BAR(4);   // waits A30,A31; keeps B30
    // interval 15: tiles 30,31 (bufs 2,3)
    loadB(31, bB); compute(2, bA); compute(3, bB);

#pragma unroll
    for (int nf = 0; nf < 4; ++nf) {
      int n = nbase + whalf * 64 + nf * 16 + ln;
      float bv = BS[n];
#pragma unroll
      for (int mf = 0; mf < 4; ++mf)
#pragma unroll
        for (int r = 0; r < 4; ++r) {
          int m = mbase + wm * 64 + mf * 16 + 4 * g + r;
          O[(size_t)m * 1024 + n] = f2bf((acc[mf][nf][r] + bv) * osc);
        }
    }
  } else {
    // z==2 swapped: A-operand = W-frags (regs), B-operand = X-frags (LDS).
    auto compute2 = [&](int cur, const bf16x8* wq) __attribute__((always_inline)) {
      bf16x8 bfx[4];
#pragma unroll
      for (int nf = 0; nf < 4; ++nf)
        bfx[nf] = *(const bf16x8*)&Al[cur][(wm * 64 + nf * 16 + ln) * 32 + (g * 8 ^ xr)];
      __builtin_amdgcn_s_setprio(1);
#pragma unroll
      for (int mf = 0; mf < 4; ++mf)
#pragma unroll
        for (int nf = 0; nf < 4; ++nf)
          acc[mf][nf] = __builtin_amdgcn_mfma_f32_16x16x32_bf16(wq[mf], bfx[nf], acc[mf][nf], 0, 0, 0);
      __builtin_amdgcn_s_setprio(0);
    };

    for (int j = 0; j < 14; j += 2) {
      int kb = 2 * j;
      stage(kb + 2, 2); stage(kb + 3, 3); loadB(kb + 1, bB); compute2(0, bA);
      loadB(kb + 2, bA); compute2(1, bB); PIPE_BAR(4);
      stage(kb + 4, 0); stage(kb + 5, 1); loadB(kb + 3, bB); compute2(2, bA);
      loadB(kb + 4, bA); compute2(3, bB); PIPE_BAR(4);
    }
    stage(30, 2); stage(31, 3); loadB(29, bB); compute2(0, bA);
    loadB(30, bA); compute2(1, bB); PIPE_BAR(4);
    loadB(31, bB); compute2(2, bA); compute2(3, bB);

#pragma unroll
    for (int mf = 0; mf < 4; ++mf)
#pragma unroll
      for (int r = 0; r < 4; ++r) {
        int dvg = nbase + whalf * 64 + mf * 16 + 4 * g + r;
        float bv = BS[dvg];
        int hh = dvg >> 6, dvl = dvg & 63;
#pragma unroll
        for (int nf = 0; nf < 4; ++nf) {
          int m = mbase + wm * 64 + nf * 16 + ln;
          int bb = m >> 11, ss = m & 2047;
          vT[((size_t)(bb * 16 + hh) * 64 + dvl) * 2048 + ss] = f2bf(acc[mf][nf][r] + bv);
        }
      }
  }
}

// ---------------------------------------------------------------------------
// Fallback proj (frozen; reads original X/W; z==2 transposed scatter).
// ---------------------------------------------------------------------------
__global__ __launch_bounds__(256)
void proj_kernel(const float* __restrict__ x0, const float* __restrict__ x1, const float* __restrict__ x2,
                 const float* __restrict__ w0, const float* __restrict__ w1, const float* __restrict__ w2,
                 const float* __restrict__ b0, const float* __restrict__ b1, const float* __restrict__ b2,
                 u16* __restrict__ o0, u16* __restrict__ o1, u16* __restrict__ vT)
{
  int p  = blockIdx.x + 8 * blockIdx.y + 512 * blockIdx.z;
  int wk = (p & 7) * 192 + (p >> 3);
  int nb = wk & 7, mb = (wk >> 3) & 63, z = wk >> 9;

  const float* X  = z == 0 ? x0 : (z == 1 ? x1 : x2);
  const float* W  = z == 0 ? w0 : (z == 1 ? w1 : w2);
  const float* BS = z == 0 ? b0 : (z == 1 ? b1 : b2);
  const float  osc = (z == 0) ? QK_SCALE : 1.0f;

  const int t = threadIdx.x;
  const int lane = t & 63, wid = t >> 6;
  const int g = lane >> 4, ln = lane & 15;
  const int wm = wid >> 1, wn = wid & 1;
  const int mbase = mb * 128, nbase = nb * 128;

  __shared__ __align__(16) u16 As[128 * 40];
  __shared__ __align__(16) u16 Bs[16 * 272];

  f32x4 acc[4][4];
#pragma unroll
  for (int i = 0; i < 4; ++i)
#pragma unroll
    for (int j = 0; j < 4; ++j) { acc[i][j][0]=0.f; acc[i][j][1]=0.f; acc[i][j][2]=0.f; acc[i][j][3]=0.f; }

  const int arow = t >> 3;
  const int ak0  = (t & 7) * 4;
  const int ap   = 8 * ((ak0 & 15) >> 2) + 4 * (ak0 >> 4);
  const int bkr  = t >> 5;
  const int bnc  = (t & 31) * 4;
  const int bnblk = bnc >> 4, bncl = bnc & 15;

  const unsigned bs_base = (unsigned)(size_t)&Bs[0];

  for (int kb = 0; kb < 32; ++kb) {
    const int kbase = kb * 32;
#pragma unroll
    for (int ps = 0; ps < 4; ++ps) {
      int row = arow + 32 * ps;
      const float4 xv = *(const float4*)&X[(size_t)(mbase + row) * 1024 + kbase + ak0];
      bf16x4 sv = { (short)f2bf(xv.x), (short)f2bf(xv.y), (short)f2bf(xv.z), (short)f2bf(xv.w) };
      *(bf16x4*)&As[row * 40 + ap] = sv;
    }
#pragma unroll
    for (int ps = 0; ps < 4; ++ps) {
      int kr = bkr + 8 * ps;
      const float4 wv = *(const float4*)&W[(size_t)(kbase + kr) * 1024 + nbase + bnc];
      bf16x4 sv = { (short)f2bf(wv.x), (short)f2bf(wv.y), (short)f2bf(wv.z), (short)f2bf(wv.w) };
      *(bf16x4*)&Bs[(bnblk * 2 + (kr >> 4)) * 272 + (kr & 15) * 16 + bncl] = sv;
    }
    __syncthreads();

    bf16x8 af[4];
#pragma unroll
    for (int mf = 0; mf < 4; ++mf)
      af[mf] = *(const bf16x8*)&As[(wm * 64 + mf * 16 + ln) * 40 + g * 8];

    bf16x8 bfv[4];
#pragma unroll
    for (int nf = 0; nf < 4; ++nf) {
      unsigned base = bs_base + (unsigned)(((wn * 4 + nf) * 2) * 544) + lane * 8;
      bf16x4 lo = ds_tr16(base);
      bf16x4 hi = ds_tr16(base + 544);
      bf16x8 bb;
      bb[0]=lo[0]; bb[1]=lo[1]; bb[2]=lo[2]; bb[3]=lo[3];
      bb[4]=hi[0]; bb[5]=hi[1]; bb[6]=hi[2]; bb[7]=hi[3];
      bfv[nf] = bb;
    }
    LGKM_FENCE();
#pragma unroll
    for (int mf = 0; mf < 4; ++mf)
#pragma unroll
      for (int nf = 0; nf < 4; ++nf)
        acc[mf][nf] = __builtin_amdgcn_mfma_f32_16x16x32_bf16(af[mf], bfv[nf], acc[mf][nf], 0, 0, 0);
    __syncthreads();
  }

#pragma unroll
  for (int nf = 0; nf < 4; ++nf) {
    int n = nbase + wn * 64 + nf * 16 + ln;
    float bv = BS[n];
#pragma unroll
    for (int mf = 0; mf < 4; ++mf)
#pragma unroll
      for (int r = 0; r < 4; ++r) {
        int m = mbase + wm * 64 + mf * 16 + 4 * g + r;
        float val = (acc[mf][nf][r] + bv) * osc;
        if (z < 2) {
          u16* O = z == 0 ? o0 : o1;
          O[(size_t)m * 1024 + n] = f2bf(val);
        } else {
          vT[((size_t)((m >> 11) * 16 + (n >> 6)) * 64 + (n & 63)) * 2048 + (m & 2047)] = f2bf(val);
        }
      }
  }
}

// ---------------------------------------------------------------------------
// Attention (R11, frozen): V^T LDS, plain b128 V-frags, no asm/fences in loop.
// 8 waves, QBLK=256, KVBLK=64, 2-barrier protocol, ones-MFMA rowsum, setprio.
// ---------------------------------------------------------------------------
__global__ __launch_bounds__(512)
void attn_kernel(const u16* __restrict__ qh, const u16* __restrict__ kh, const u16* __restrict__ vT,
                 float* __restrict__ out)
{
  int p  = blockIdx.x + 8 * blockIdx.y + 128 * blockIdx.z;
  int wk = (p & 7) * 64 + (p >> 3);
  int qt = wk & 7, h = (wk >> 3) & 15, b = wk >> 7;

  const int t = threadIdx.x;
  const int lane = t & 63, wid = t >> 6;
  const int g = lane >> 4, ln = lane & 15;
  const size_t bS = (size_t)b * S_TOT;
  const int qwin = qt * 256 + wid * 32;

  __shared__ __align__(16) u16 Ks[64 * 72];
  __shared__ __align__(16) u16 Vt[64 * 72];

  bf16x8 qf[2][2];
#pragma unroll
  for (int nf = 0; nf < 2; ++nf) {
    const u16* qrow = &qh[(bS + qwin + nf * 16 + ln) * HD + h * 64];
#pragma unroll
    for (int kk = 0; kk < 2; ++kk) {
      bf16x4 lo = *(const bf16x4*)&qrow[kk * 32 + 4 * g];
      bf16x4 hi = *(const bf16x4*)&qrow[kk * 32 + 4 * g + 16];
      bf16x8 qq;
      qq[0]=lo[0]; qq[1]=lo[1]; qq[2]=lo[2]; qq[3]=lo[3];
      qq[4]=hi[0]; qq[5]=hi[1]; qq[6]=hi[2]; qq[7]=hi[3];
      qf[nf][kk] = qq;
    }
  }

  bf16x8 ones;
#pragma unroll
  for (int j = 0; j < 8; ++j) ones[j] = (short)0x3F80;

  f32x4 o[2][4];
#pragma unroll
  for (int i = 0; i < 2; ++i)
#pragma unroll
    for (int j = 0; j < 4; ++j) { o[i][j][0]=0.f; o[i][j][1]=0.f; o[i][j][2]=0.f; o[i][j][3]=0.f; }
  f32x4 o1[2];
  o1[0][0]=0.f; o1[0][1]=0.f; o1[0][2]=0.f; o1[0][3]=0.f;
  o1[1][0]=0.f; o1[1][1]=0.f; o1[1][2]=0.f; o1[1][3]=0.f;

  const int skv = t >> 4;
  const int sd0 = (t & 15) * 4;
  const int kpos = 32 * (sd0 >> 5) + 8 * ((sd0 & 15) >> 2) + 4 * ((sd0 >> 4) & 1);
  u16* ksw[2];
  ksw[0] = &Ks[skv * 72 + kpos];
  ksw[1] = &Ks[(skv + 32) * 72 + kpos];
  const u16* kp = &kh[(bS + skv) * HD + h * 64 + sd0];

  const int vdv  = t >> 3;
  const int vkv8 = (t & 7) * 8;
  const int vp0  = 32 * (vkv8 >> 5) + 8 * ((vkv8 & 15) >> 2) + 4 * ((vkv8 >> 4) & 1);
  const int vkv4 = vkv8 + 4;
  const int vp1  = 32 * (vkv4 >> 5) + 8 * ((vkv4 & 15) >> 2) + 4 * ((vkv4 >> 4) & 1);
  u16* vsw0 = &Vt[vdv * 72 + vp0];
  u16* vsw1 = &Vt[vdv * 72 + vp1];
  const u16* vp = &vT[((size_t)(b * 16 + h) * 64 + vdv) * 2048 + vkv8];

  const size_t KSTEP = (size_t)64 * HD, C32 = (size_t)32 * HD;

  bf16x4 kr[2];
  kr[0] = *(const bf16x4*)kp; kr[1] = *(const bf16x4*)(kp + C32);
  bf16x8 vr = *(const bf16x8*)vp;
  kp += KSTEP; vp += 64;

  for (int it = 0; it < 32; ++it) {
    *(bf16x4*)ksw[0] = kr[0];
    *(bf16x4*)ksw[1] = kr[1];
    bf16x4 vlo = { vr[0], vr[1], vr[2], vr[3] };
    bf16x4 vhi = { vr[4], vr[5], vr[6], vr[7] };
    *(bf16x4*)vsw0 = vlo;
    *(bf16x4*)vsw1 = vhi;
    __syncthreads();

    if (it < 31) {
      kr[0] = *(const bf16x4*)kp; kr[1] = *(const bf16x4*)(kp + C32);
      vr = *(const bf16x8*)vp;
      kp += KSTEP; vp += 64;
    }

#pragma unroll
    for (int s = 0; s < 2; ++s) {
      bf16x8 kf[2][2];
#pragma unroll
      for (int mf = 0; mf < 2; ++mf)
#pragma unroll
        for (int kk = 0; kk < 2; ++kk)
          kf[mf][kk] = *(const bf16x8*)&Ks[(s * 32 + mf * 16 + ln) * 72 + kk * 32 + 8 * g];

      f32x4 sc[2][2];
      __builtin_amdgcn_s_setprio(1);
#pragma unroll
      for (int mf = 0; mf < 2; ++mf)
#pragma unroll
        for (int nf = 0; nf < 2; ++nf) {
          f32x4 a; a[0]=0.f; a[1]=0.f; a[2]=0.f; a[3]=0.f;
#pragma unroll
          for (int kk = 0; kk < 2; ++kk)
            a = __builtin_amdgcn_mfma_f32_16x16x32_bf16(kf[mf][kk], qf[nf][kk], a, 0, 0, 0);
          sc[mf][nf] = a;
        }
      __builtin_amdgcn_s_setprio(0);

      bf16x8 vf[4];
#pragma unroll
      for (int nf = 0; nf < 4; ++nf)
        vf[nf] = *(const bf16x8*)&Vt[(nf * 16 + ln) * 72 + s * 32 + 8 * g];

      bf16x8 pa[2];
#pragma unroll
      for (int nf = 0; nf < 2; ++nf) {
        float pv[2][4];
#pragma unroll
        for (int mf = 0; mf < 2; ++mf)
#pragma unroll
          for (int r = 0; r < 4; ++r)
            pv[mf][r] = EXP2(sc[mf][nf][r]);
        union { u32x4 u; bf16x8 b; } pk;
        pk.u[0] = cvt_pk_bf16(pv[0][0], pv[0][1]);
        pk.u[1] = cvt_pk_bf16(pv[0][2], pv[0][3]);
        pk.u[2] = cvt_pk_bf16(pv[1][0], pv[1][1]);
        pk.u[3] = cvt_pk_bf16(pv[1][2], pv[1][3]);
        pa[nf] = pk.b;
      }

      __builtin_amdgcn_s_setprio(1);
#pragma unroll
      for (int mq = 0; mq < 2; ++mq) {
#pragma unroll
        for (int nf = 0; nf < 4; ++nf)
          o[mq][nf] = __builtin_amdgcn_mfma_f32_16x16x32_bf16(pa[mq], vf[nf], o[mq][nf], 0, 0, 0);
        o1[mq] = __builtin_amdgcn_mfma_f32_16x16x32_bf16(pa[mq], ones, o1[mq], 0, 0, 0);
      }
      __builtin_amdgcn_s_setprio(0);
    }
    __syncthreads();
  }

#pragma unroll
  for (int mq = 0; mq < 2; ++mq)
#pragma unroll
    for (int r = 0; r < 4; ++r) {
      float inv = 1.0f / o1[mq][r];
      int qrow = qwin + mq * 16 + 4 * g + r;
#pragma unroll
      for (int nf = 0; nf < 4; ++nf)
        out[(bS + qrow) * HD + h * 64 + nf * 16 + ln] = o[mq][nf][r] * inv;
    }
}

extern "C" void kernel_launch(void* const* d_in, const int* in_sizes, int n_in,
                              void* d_out, int out_size, void* d_ws, size_t ws_size,
                              hipStream_t stream) {
  const float* q  = (const float*)d_in[0];
  const float* k  = (const float*)d_in[1];
  const float* v  = (const float*)d_in[2];
  const float* Wq = (const float*)d_in[3];
  const float* bq = (const float*)d_in[4];
  const float* Wk = (const float*)d_in[5];
  const float* bk = (const float*)d_in[6];
  const float* Wv = (const float*)d_in[7];
  const float* bv = (const float*)d_in[8];
  float* out = (float*)d_out;

  u16* qh = (u16*)d_ws;
  u16* kh = qh + (size_t)8192 * 1024;
  u16* vT = kh + (size_t)8192 * 1024;     // [b][h][dv][seq]

  const size_t XB_OFF = (size_t)3 * 8192 * 1024;
  const size_t WT_OFF = XB_OFF + (size_t)3 * 8192 * 1024;
  const size_t NEED   = (WT_OFF + (size_t)3 * 1024 * 1024) * 2;

  if (ws_size >= NEED) {
    u16* Xb = (u16*)d_ws + XB_OFF;
    u16* Wt = (u16*)d_ws + WT_OFF;
    conv_kernel<<<dim3(1152, 3), 256, 0, stream>>>(q, k, v, Wq, Wk, Wv, Xb, Wt);
    gemm_kernel<<<dim3(8, 32, 3), 512, 0, stream>>>(Xb, Wt, bq, bk, bv, qh, kh, vT);
  } else {
    proj_kernel<<<dim3(8, 64, 3), 256, 0, stream>>>(q, k, v, Wq, Wk, Wv, bq, bk, bv, qh, kh, vT);
  }
  attn_kernel<<<dim3(8, 16, 4), 512, 0, stream>>>(qh, kh, vT, out);
}

// Round 17
// 152.895 us; speedup vs baseline: 1.1966x; 1.1966x over previous
//
#include <hip/hip_runtime.h>
#include <hip/hip_bf16.h>

// MultiHeadAttention: B=4 S=2048 D=1024 H=16 DK=DV=64 scale=8
// R17: delete the X re-layout pass (150MB HBM ~24us). gemm stages A DIRECTLY
// from fp32 X: 4x float4/thread/phase -> f2bf -> swizzled ds_write (k-perm +
// XOR swizzle applied at write; read side unchanged). Single-buffer 2-barrier
// protocol (attn-proven R8-R11). B stays register-direct from bf16 Wt (R15).
// conv = W-pass only (~12MB, ~3us). R16's 8-wave reshape regressed (97us) ->
// gemm tile/waves reverted to R15 config. attn/proj frozen.

typedef unsigned short u16;
typedef unsigned int   u32;
typedef short bf16x8 __attribute__((ext_vector_type(8)));
typedef short bf16x4 __attribute__((ext_vector_type(4)));
typedef float f32x4  __attribute__((ext_vector_type(4)));
typedef u32   u32x4  __attribute__((ext_vector_type(4)));

#define S_TOT 2048
#define HD    1024
#define QK_SCALE 0.18033688f   // log2(e)/8

#if __has_builtin(__builtin_amdgcn_exp2f)
#define EXP2(x) __builtin_amdgcn_exp2f(x)
#else
#define EXP2(x) exp2f(x)
#endif

__device__ __forceinline__ u16 f2bf(float f) {
  union { float f; unsigned u; } v; v.f = f;
  unsigned r = v.u + 0x7FFFu + ((v.u >> 16) & 1u);
  return (u16)(r >> 16);
}

__device__ __forceinline__ u32 cvt_pk_bf16(float lo, float hi) {
  u32 r;
  asm("v_cvt_pk_bf16_f32 %0, %1, %2" : "=v"(r) : "v"(lo), "v"(hi));
  return r;
}

__device__ __forceinline__ bf16x4 ds_tr16(unsigned a) {
  bf16x4 d;
  asm volatile("ds_read_b64_tr_b16 %0, %1" : "=v"(d) : "v"(a) : "memory");
  return d;
}

// rule #18 fence — used ONLY by the fallback proj
#define LGKM_FENCE() do { asm volatile("s_waitcnt lgkmcnt(0)" ::: "memory"); \
                          __builtin_amdgcn_sched_barrier(0); } while (0)

// ---------------------------------------------------------------------------
// conv_kernel: W-pass only. Wt: W^T tiles [(nb*32+kb)][128 n][32 kperm].
// ---------------------------------------------------------------------------
__global__ __launch_bounds__(256)
void conv_kernel(const float* __restrict__ w0, const float* __restrict__ w1, const float* __restrict__ w2,
                 u16* __restrict__ Wt)
{
  const int z = blockIdx.y;
  const int t = threadIdx.x;
  const float* W = z == 0 ? w0 : (z == 1 ? w1 : w2);
  u16* Wz = Wt + (size_t)z * 1048576;
  int tid = blockIdx.x * 256 + t;              // 0..32767
#pragma unroll
  for (int i = 0; i < 8; ++i) {
    int c = tid + i * 32768;                   // 262144 total: (n, k4)
    int n = c & 1023, k4 = (c >> 10) * 4;
    float wv0 = W[(size_t)(k4 + 0) * 1024 + n];
    float wv1 = W[(size_t)(k4 + 1) * 1024 + n];
    float wv2 = W[(size_t)(k4 + 2) * 1024 + n];
    float wv3 = W[(size_t)(k4 + 3) * 1024 + n];
    int kl = k4 & 31;
    int kp = 8 * ((kl & 15) >> 2) + 4 * ((kl >> 4) & 1);
    int off = ((n >> 7) * 32 + (k4 >> 5)) * 4096 + (n & 127) * 32 + kp;
    bf16x4 sv = { (short)f2bf(wv0), (short)f2bf(wv1), (short)f2bf(wv2), (short)f2bf(wv3) };
    *(bf16x4*)&Wz[off] = sv;
  }
}

// ---------------------------------------------------------------------------
// gemm_kernel R17: A staged from fp32 X (cvt + swizzled ds_write), single
// 8KB LDS buffer, 2-barrier protocol; B global->reg ping-pong from Wt.
// z<2: natural out. z==2: swapped operands -> vT.
// ---------------------------------------------------------------------------
__global__ __launch_bounds__(256)
void gemm_kernel(const float* __restrict__ x0, const float* __restrict__ x1, const float* __restrict__ x2,
                 const u16* __restrict__ Wt,
                 const float* __restrict__ b0, const float* __restrict__ b1, const float* __restrict__ b2,
                 u16* __restrict__ o0, u16* __restrict__ o1, u16* __restrict__ vT)
{
  // bijective XCD swizzle: nwg=1536 (%8==0)
  int p  = blockIdx.x + 8 * blockIdx.y + 512 * blockIdx.z;
  int wk = (p & 7) * 192 + (p >> 3);
  int nb = wk & 7, mb = (wk >> 3) & 63, z = wk >> 9;

  const float* X  = z == 0 ? x0 : (z == 1 ? x1 : x2);
  const u16*   Wz = Wt + (size_t)z * 1048576;
  const float* BS = z == 0 ? b0 : (z == 1 ? b1 : b2);
  const float  osc = (z == 0) ? QK_SCALE : 1.0f;

  const int t = threadIdx.x;
  const int lane = t & 63, wid = t >> 6;
  const int g = lane >> 4, ln = lane & 15;
  const int mbase = mb * 128, nbase = nb * 128;
  const int xr = (ln & 6) << 2;                  // A read-side swizzle (u16)

  __shared__ __align__(16) u16 Al[128 * 32];     // 8KB single buffer

  f32x4 acc[4][4];
#pragma unroll
  for (int i = 0; i < 4; ++i)
#pragma unroll
    for (int j = 0; j < 4; ++j) { acc[i][j][0]=0.f; acc[i][j][1]=0.f; acc[i][j][2]=0.f; acc[i][j][3]=0.f; }

  // A staging: arow = t>>3 (+32*ps), ak0 = (t&7)*4 -> 128B contiguous per row
  const int arow = t >> 3;
  const int ak0  = (t & 7) * 4;
  const int ap   = 8 * ((ak0 & 15) >> 2) + 4 * ((ak0 >> 4) & 1);  // k-perm
  const int axr  = (arow & 6) << 2;                               // write-side swizzle
  const int apw  = ap ^ axr;
  const float* xp = &X[(size_t)(mbase + arow) * 1024 + ak0];

  // B fragment source (register-direct from Wt)
  const int whalf = wid & 1;
  const u16* wfp = Wz + (size_t)(nb * 32) * 4096 + (whalf * 64 + ln) * 32 + g * 8;
  auto loadB = [&](int kb, bf16x8* dst) __attribute__((always_inline)) {
#pragma unroll
    for (int nf = 0; nf < 4; ++nf)
      dst[nf] = *(const bf16x8*)(wfp + (size_t)kb * 4096 + nf * 512);
  };

  float4 xrg[4];
  bf16x8 bA[4], bB[4];

  // prologue: tile 0 into regs (X + B)
#pragma unroll
  for (int ps = 0; ps < 4; ++ps)
    xrg[ps] = *(const float4*)(xp + (size_t)(32 * ps) * 1024);
  xp += 32;
  loadB(0, bA);

  const int wm = wid >> 1;

  // one phase: write tile kb (from regs), barrier, load tile kb+1, compute, barrier
  auto phase = [&](int kb, const bf16x8* bq, bf16x8* bnext, bool swapped)
      __attribute__((always_inline)) {
    // cvt + swizzled LDS write of tile kb
#pragma unroll
    for (int ps = 0; ps < 4; ++ps) {
      int row = arow + 32 * ps;
      bf16x4 sv = { (short)f2bf(xrg[ps].x), (short)f2bf(xrg[ps].y),
                    (short)f2bf(xrg[ps].z), (short)f2bf(xrg[ps].w) };
      *(bf16x4*)&Al[row * 32 + apw] = sv;
    }
    __syncthreads();                             // barrier #1: tile kb visible

    if (kb < 31) {                               // issue tile kb+1 loads
#pragma unroll
      for (int ps = 0; ps < 4; ++ps)
        xrg[ps] = *(const float4*)(xp + (size_t)(32 * ps) * 1024);
      xp += 32;
      loadB(kb + 1, bnext);
    }

    bf16x8 af[4];
#pragma unroll
    for (int mf = 0; mf < 4; ++mf)
      af[mf] = *(const bf16x8*)&Al[(wm * 64 + mf * 16 + ln) * 32 + (g * 8 ^ xr)];
    __builtin_amdgcn_s_setprio(1);
    if (!swapped) {
#pragma unroll
      for (int mf = 0; mf < 4; ++mf)
#pragma unroll
        for (int nf = 0; nf < 4; ++nf)
          acc[mf][nf] = __builtin_amdgcn_mfma_f32_16x16x32_bf16(af[mf], bq[nf], acc[mf][nf], 0, 0, 0);
    } else {
#pragma unroll
      for (int mf = 0; mf < 4; ++mf)
#pragma unroll
        for (int nf = 0; nf < 4; ++nf)
          acc[mf][nf] = __builtin_amdgcn_mfma_f32_16x16x32_bf16(bq[mf], af[nf], acc[mf][nf], 0, 0, 0);
    }
    __builtin_amdgcn_s_setprio(0);
    __syncthreads();                             // barrier #2: reads done
  };

  const bool swapped = (z == 2);
  for (int it = 0; it < 16; ++it) {              // unroll x2: static ping-pong
    phase(2 * it,     bA, bB, swapped);
    phase(2 * it + 1, bB, bA, swapped);
  }

  if (!swapped) {
    u16* O = z == 0 ? o0 : o1;
#pragma unroll
    for (int nf = 0; nf < 4; ++nf) {
      int n = nbase + whalf * 64 + nf * 16 + ln;
      float bv = BS[n];
#pragma unroll
      for (int mf = 0; mf < 4; ++mf)
#pragma unroll
        for (int r = 0; r < 4; ++r) {
          int m = mbase + wm * 64 + mf * 16 + 4 * g + r;
          O[(size_t)m * 1024 + n] = f2bf((acc[mf][nf][r] + bv) * osc);
        }
    }
  } else {
    // swapped: acc row = dv frag (from W), col = seq (ln) -> transposed store
#pragma unroll
    for (int mf = 0; mf < 4; ++mf)
#pragma unroll
      for (int r = 0; r < 4; ++r) {
        int dvg = nbase + whalf * 64 + mf * 16 + 4 * g + r;
        float bv = BS[dvg];
        int hh = dvg >> 6, dvl = dvg & 63;
#pragma unroll
        for (int nf = 0; nf < 4; ++nf) {
          int m = mbase + wm * 64 + nf * 16 + ln;
          int bb = m >> 11, ss = m & 2047;
          vT[((size_t)(bb * 16 + hh) * 64 + dvl) * 2048 + ss] = f2bf(acc[mf][nf][r] + bv);
        }
      }
  }
}

// ---------------------------------------------------------------------------
// Fallback proj (frozen; reads original X/W; z==2 transposed scatter).
// ---------------------------------------------------------------------------
__global__ __launch_bounds__(256)
void proj_kernel(const float* __restrict__ x0, const float* __restrict__ x1, const float* __restrict__ x2,
                 const float* __restrict__ w0, const float* __restrict__ w1, const float* __restrict__ w2,
                 const float* __restrict__ b0, const float* __restrict__ b1, const float* __restrict__ b2,
                 u16* __restrict__ o0, u16* __restrict__ o1, u16* __restrict__ vT)
{
  int p  = blockIdx.x + 8 * blockIdx.y + 512 * blockIdx.z;
  int wk = (p & 7) * 192 + (p >> 3);
  int nb = wk & 7, mb = (wk >> 3) & 63, z = wk >> 9;

  const float* X  = z == 0 ? x0 : (z == 1 ? x1 : x2);
  const float* W  = z == 0 ? w0 : (z == 1 ? w1 : w2);
  const float* BS = z == 0 ? b0 : (z == 1 ? b1 : b2);
  const float  osc = (z == 0) ? QK_SCALE : 1.0f;

  const int t = threadIdx.x;
  const int lane = t & 63, wid = t >> 6;
  const int g = lane >> 4, ln = lane & 15;
  const int wm = wid >> 1, wn = wid & 1;
  const int mbase = mb * 128, nbase = nb * 128;

  __shared__ __align__(16) u16 As[128 * 40];
  __shared__ __align__(16) u16 Bs[16 * 272];

  f32x4 acc[4][4];
#pragma unroll
  for (int i = 0; i < 4; ++i)
#pragma unroll
    for (int j = 0; j < 4; ++j) { acc[i][j][0]=0.f; acc[i][j][1]=0.f; acc[i][j][2]=0.f; acc[i][j][3]=0.f; }

  const int arow = t >> 3;
  const int ak0  = (t & 7) * 4;
  const int ap   = 8 * ((ak0 & 15) >> 2) + 4 * (ak0 >> 4);
  const int bkr  = t >> 5;
  const int bnc  = (t & 31) * 4;
  const int bnblk = bnc >> 4, bncl = bnc & 15;

  const unsigned bs_base = (unsigned)(size_t)&Bs[0];

  for (int kb = 0; kb < 32; ++kb) {
    const int kbase = kb * 32;
#pragma unroll
    for (int ps = 0; ps < 4; ++ps) {
      int row = arow + 32 * ps;
      const float4 xv = *(const float4*)&X[(size_t)(mbase + row) * 1024 + kbase + ak0];
      bf16x4 sv = { (short)f2bf(xv.x), (short)f2bf(xv.y), (short)f2bf(xv.z), (short)f2bf(xv.w) };
      *(bf16x4*)&As[row * 40 + ap] = sv;
    }
#pragma unroll
    for (int ps = 0; ps < 4; ++ps) {
      int kr = bkr + 8 * ps;
      const float4 wv = *(const float4*)&W[(size_t)(kbase + kr) * 1024 + nbase + bnc];
      bf16x4 sv = { (short)f2bf(wv.x), (short)f2bf(wv.y), (short)f2bf(wv.z), (short)f2bf(wv.w) };
      *(bf16x4*)&Bs[(bnblk * 2 + (kr >> 4)) * 272 + (kr & 15) * 16 + bncl] = sv;
    }
    __syncthreads();

    bf16x8 af[4];
#pragma unroll
    for (int mf = 0; mf < 4; ++mf)
      af[mf] = *(const bf16x8*)&As[(wm * 64 + mf * 16 + ln) * 40 + g * 8];

    bf16x8 bfv[4];
#pragma unroll
    for (int nf = 0; nf < 4; ++nf) {
      unsigned base = bs_base + (unsigned)(((wn * 4 + nf) * 2) * 544) + lane * 8;
      bf16x4 lo = ds_tr16(base);
      bf16x4 hi = ds_tr16(base + 544);
      bf16x8 bb;
      bb[0]=lo[0]; bb[1]=lo[1]; bb[2]=lo[2]; bb[3]=lo[3];
      bb[4]=hi[0]; bb[5]=hi[1]; bb[6]=hi[2]; bb[7]=hi[3];
      bfv[nf] = bb;
    }
    LGKM_FENCE();
#pragma unroll
    for (int mf = 0; mf < 4; ++mf)
#pragma unroll
      for (int nf = 0; nf < 4; ++nf)
        acc[mf][nf] = __builtin_amdgcn_mfma_f32_16x16x32_bf16(af[mf], bfv[nf], acc[mf][nf], 0, 0, 0);
    __syncthreads();
  }

#pragma unroll
  for (int nf = 0; nf < 4; ++nf) {
    int n = nbase + wn * 64 + nf * 16 + ln;
    float bv = BS[n];
#pragma unroll
    for (int mf = 0; mf < 4; ++mf)
#pragma unroll
      for (int r = 0; r < 4; ++r) {
        int m = mbase + wm * 64 + mf * 16 + 4 * g + r;
        float val = (acc[mf][nf][r] + bv) * osc;
        if (z < 2) {
          u16* O = z == 0 ? o0 : o1;
          O[(size_t)m * 1024 + n] = f2bf(val);
        } else {
          vT[((size_t)((m >> 11) * 16 + (n >> 6)) * 64 + (n & 63)) * 2048 + (m & 2047)] = f2bf(val);
        }
      }
  }
}

// ---------------------------------------------------------------------------
// Attention (R11, frozen): V^T LDS, plain b128 V-frags, no asm/fences in loop.
// 8 waves, QBLK=256, KVBLK=64, 2-barrier protocol, ones-MFMA rowsum, setprio.
// ---------------------------------------------------------------------------
__global__ __launch_bounds__(512)
void attn_kernel(const u16* __restrict__ qh, const u16* __restrict__ kh, const u16* __restrict__ vT,
                 float* __restrict__ out)
{
  int p  = blockIdx.x + 8 * blockIdx.y + 128 * blockIdx.z;
  int wk = (p & 7) * 64 + (p >> 3);
  int qt = wk & 7, h = (wk >> 3) & 15, b = wk >> 7;

  const int t = threadIdx.x;
  const int lane = t & 63, wid = t >> 6;
  const int g = lane >> 4, ln = lane & 15;
  const size_t bS = (size_t)b * S_TOT;
  const int qwin = qt * 256 + wid * 32;

  __shared__ __align__(16) u16 Ks[64 * 72];
  __shared__ __align__(16) u16 Vt[64 * 72];

  bf16x8 qf[2][2];
#pragma unroll
  for (int nf = 0; nf < 2; ++nf) {
    const u16* qrow = &qh[(bS + qwin + nf * 16 + ln) * HD + h * 64];
#pragma unroll
    for (int kk = 0; kk < 2; ++kk) {
      bf16x4 lo = *(const bf16x4*)&qrow[kk * 32 + 4 * g];
      bf16x4 hi = *(const bf16x4*)&qrow[kk * 32 + 4 * g + 16];
      bf16x8 qq;
      qq[0]=lo[0]; qq[1]=lo[1]; qq[2]=lo[2]; qq[3]=lo[3];
      qq[4]=hi[0]; qq[5]=hi[1]; qq[6]=hi[2]; qq[7]=hi[3];
      qf[nf][kk] = qq;
    }
  }

  bf16x8 ones;
#pragma unroll
  for (int j = 0; j < 8; ++j) ones[j] = (short)0x3F80;

  f32x4 o[2][4];
#pragma unroll
  for (int i = 0; i < 2; ++i)
#pragma unroll
    for (int j = 0; j < 4; ++j) { o[i][j][0]=0.f; o[i][j][1]=0.f; o[i][j][2]=0.f; o[i][j][3]=0.f; }
  f32x4 o1[2];
  o1[0][0]=0.f; o1[0][1]=0.f; o1[0][2]=0.f; o1[0][3]=0.f;
  o1[1][0]=0.f; o1[1][1]=0.f; o1[1][2]=0.f; o1[1][3]=0.f;

  const int skv = t >> 4;
  const int sd0 = (t & 15) * 4;
  const int kpos = 32 * (sd0 >> 5) + 8 * ((sd0 & 15) >> 2) + 4 * ((sd0 >> 4) & 1);
  u16* ksw[2];
  ksw[0] = &Ks[skv * 72 + kpos];
  ksw[1] = &Ks[(skv + 32) * 72 + kpos];
  const u16* kp = &kh[(bS + skv) * HD + h * 64 + sd0];

  const int vdv  = t >> 3;
  const int vkv8 = (t & 7) * 8;
  const int vp0  = 32 * (vkv8 >> 5) + 8 * ((vkv8 & 15) >> 2) + 4 * ((vkv8 >> 4) & 1);
  const int vkv4 = vkv8 + 4;
  const int vp1  = 32 * (vkv4 >> 5) + 8 * ((vkv4 & 15) >> 2) + 4 * ((vkv4 >> 4) & 1);
  u16* vsw0 = &Vt[vdv * 72 + vp0];
  u16* vsw1 = &Vt[vdv * 72 + vp1];
  const u16* vp = &vT[((size_t)(b * 16 + h) * 64 + vdv) * 2048 + vkv8];

  const size_t KSTEP = (size_t)64 * HD, C32 = (size_t)32 * HD;

  bf16x4 kr[2];
  kr[0] = *(const bf16x4*)kp; kr[1] = *(const bf16x4*)(kp + C32);
  bf16x8 vr = *(const bf16x8*)vp;
  kp += KSTEP; vp += 64;

  for (int it = 0; it < 32; ++it) {
    *(bf16x4*)ksw[0] = kr[0];
    *(bf16x4*)ksw[1] = kr[1];
    bf16x4 vlo = { vr[0], vr[1], vr[2], vr[3] };
    bf16x4 vhi = { vr[4], vr[5], vr[6], vr[7] };
    *(bf16x4*)vsw0 = vlo;
    *(bf16x4*)vsw1 = vhi;
    __syncthreads();

    if (it < 31) {
      kr[0] = *(const bf16x4*)kp; kr[1] = *(const bf16x4*)(kp + C32);
      vr = *(const bf16x8*)vp;
      kp += KSTEP; vp += 64;
    }

#pragma unroll
    for (int s = 0; s < 2; ++s) {
      bf16x8 kf[2][2];
#pragma unroll
      for (int mf = 0; mf < 2; ++mf)
#pragma unroll
        for (int kk = 0; kk < 2; ++kk)
          kf[mf][kk] = *(const bf16x8*)&Ks[(s * 32 + mf * 16 + ln) * 72 + kk * 32 + 8 * g];

      f32x4 sc[2][2];
      __builtin_amdgcn_s_setprio(1);
#pragma unroll
      for (int mf = 0; mf < 2; ++mf)
#pragma unroll
        for (int nf = 0; nf < 2; ++nf) {
          f32x4 a; a[0]=0.f; a[1]=0.f; a[2]=0.f; a[3]=0.f;
#pragma unroll
          for (int kk = 0; kk < 2; ++kk)
            a = __builtin_amdgcn_mfma_f32_16x16x32_bf16(kf[mf][kk], qf[nf][kk], a, 0, 0, 0);
          sc[mf][nf] = a;
        }
      __builtin_amdgcn_s_setprio(0);

      bf16x8 vf[4];
#pragma unroll
      for (int nf = 0; nf < 4; ++nf)
        vf[nf] = *(const bf16x8*)&Vt[(nf * 16 + ln) * 72 + s * 32 + 8 * g];

      bf16x8 pa[2];
#pragma unroll
      for (int nf = 0; nf < 2; ++nf) {
        float pv[2][4];
#pragma unroll
        for (int mf = 0; mf < 2; ++mf)
#pragma unroll
          for (int r = 0; r < 4; ++r)
            pv[mf][r] = EXP2(sc[mf][nf][r]);
        union { u32x4 u; bf16x8 b; } pk;
        pk.u[0] = cvt_pk_bf16(pv[0][0], pv[0][1]);
        pk.u[1] = cvt_pk_bf16(pv[0][2], pv[0][3]);
        pk.u[2] = cvt_pk_bf16(pv[1][0], pv[1][1]);
        pk.u[3] = cvt_pk_bf16(pv[1][2], pv[1][3]);
        pa[nf] = pk.b;
      }

      __builtin_amdgcn_s_setprio(1);
#pragma unroll
      for (int mq = 0; mq < 2; ++mq) {
#pragma unroll
        for (int nf = 0; nf < 4; ++nf)
          o[mq][nf] = __builtin_amdgcn_mfma_f32_16x16x32_bf16(pa[mq], vf[nf], o[mq][nf], 0, 0, 0);
        o1[mq] = __builtin_amdgcn_mfma_f32_16x16x32_bf16(pa[mq], ones, o1[mq], 0, 0, 0);
      }
      __builtin_amdgcn_s_setprio(0);
    }
    __syncthreads();
  }

#pragma unroll
  for (int mq = 0; mq < 2; ++mq)
#pragma unroll
    for (int r = 0; r < 4; ++r) {
      float inv = 1.0f / o1[mq][r];
      int qrow = qwin + mq * 16 + 4 * g + r;
#pragma unroll
      for (int nf = 0; nf < 4; ++nf)
        out[(bS + qrow) * HD + h * 64 + nf * 16 + ln] = o[mq][nf][r] * inv;
    }
}

extern "C" void kernel_launch(void* const* d_in, const int* in_sizes, int n_in,
                              void* d_out, int out_size, void* d_ws, size_t ws_size,
                              hipStream_t stream) {
  const float* q  = (const float*)d_in[0];
  const float* k  = (const float*)d_in[1];
  const float* v  = (const float*)d_in[2];
  const float* Wq = (const float*)d_in[3];
  const float* bq = (const float*)d_in[4];
  const float* Wk = (const float*)d_in[5];
  const float* bk = (const float*)d_in[6];
  const float* Wv = (const float*)d_in[7];
  const float* bv = (const float*)d_in[8];
  float* out = (float*)d_out;

  u16* qh = (u16*)d_ws;
  u16* kh = qh + (size_t)8192 * 1024;
  u16* vT = kh + (size_t)8192 * 1024;     // [b][h][dv][seq]

  const size_t XB_OFF = (size_t)3 * 8192 * 1024;
  const size_t WT_OFF = XB_OFF + (size_t)3 * 8192 * 1024;
  const size_t NEED   = (WT_OFF + (size_t)3 * 1024 * 1024) * 2;

  if (ws_size >= NEED) {
    u16* Wt = (u16*)d_ws + WT_OFF;
    conv_kernel<<<dim3(128, 3), 256, 0, stream>>>(Wq, Wk, Wv, Wt);
    gemm_kernel<<<dim3(8, 64, 3), 256, 0, stream>>>(q, k, v, Wt, bq, bk, bv, qh, kh, vT);
  } else {
    proj_kernel<<<dim3(8, 64, 3), 256, 0, stream>>>(q, k, v, Wq, Wk, Wv, bq, bk, bv, qh, kh, vT);
  }
  attn_kernel<<<dim3(8, 16, 4), 512, 0, stream>>>(qh, kh, vT, out);
}